// Round 6
// baseline (98.604 us; speedup 1.0000x reference)
//
#include <hip/hip_runtime.h>
#include <math.h>

#define TPB 256
#define IB 64
#define EPSF 1e-15f

// Fused prep + O(n^2) pair kernel. ZERO LDS, ZERO barriers: each wave holds the
// whole 128-element i-span in 6 VGPRs (lane l owns i = 2l,2l+1) and the inner
// loop broadcasts lane k's values via v_readlane (VALU->SGPR, no memory pipe,
// no lgkmcnt). This removes the per-k-iter ds_read latency + per-CU LDS-pipe
// contention that R1-R5 evidence isolated as the non-issue-bound stall.
//
// Math (verbatim from the proven 82.5us kernel, bit-identical accumulation):
// Rs = (g1+log y)/(h*sqrt(2 ln 2)) so exp(-0.5*((R_i-R_j)/h)^2) = exp2(-dr^2).
// A_j = sum_i d_i*e;  L*Phi = 0.5*L + copysign(L,dr)*(0.5-u),
// u = upper-tail Q(|dr_true|) via A&S 7.1.25 3-term erfc (|eps|<=2.5e-5),
// reusing the SAME exp2. The 0.5*sum(L) over this block's span is folded in
// once (spans partition i, so the block sum telescopes to 0.5*sum_all L).
__global__ __launch_bounds__(TPB, 8) void pair_kernel(
    const float* __restrict__ m_z, const float* __restrict__ y,
    const float* __restrict__ delta, float2* __restrict__ P,
    float* __restrict__ out, float inv_hk, int n, int span) {
    const int tid = threadIdx.x;
    const int lane = tid & 63;
    const int j = blockIdx.x * TPB + tid;
    const float2* __restrict__ mz2 = (const float2*)m_z;

    // j-row value
    const float2 gj = mz2[j];
    const float Rj = (gj.x + __logf(y[j])) * inv_hk;

    // per-wave span ownership: lane l holds i = ibase+2l, ibase+2l+1
    const int ibase = blockIdx.y * span;          // span == 128
    const int p = (ibase >> 1) + lane;            // pair index
    const float4 gg = ((const float4*)m_z)[p];    // {g1_0,g2_0,g1_1,g2_1}
    const float2 yv = ((const float2*)y)[p];
    const float2 dv = ((const float2*)delta)[p];
    const float vR0 = (gg.x + __logf(yv.x)) * inv_hk;
    const float vR1 = (gg.z + __logf(yv.y)) * inv_hk;
    const float vL0 = __expf(gg.y - gg.x);
    const float vL1 = __expf(gg.w - gg.z);
    const float vD0 = dv.x;
    const float vD1 = dv.y;

    // wave-local sum of L over the span (each wave owns the full span)
    float s = vL0 + vL1;
    for (int o = 32; o > 0; o >>= 1) s += __shfl_down(s, o, 64);
    const float sLtot = __int_as_float(
        __builtin_amdgcn_readfirstlane(__float_as_int(s)));

    if (j == 0 && blockIdx.y == 0) out[0] = 0.0f;  // harness poisons d_out

    float a0 = 0.0f, a1 = 0.0f, b0 = 0.5f * sLtot, b1 = 0.0f;
#pragma unroll 4
    for (int k = 0; k < 64; ++k) {
        // wave-uniform broadcast of lane k's i-data: VALU readlane -> SGPR
        const float r0 = __int_as_float(__builtin_amdgcn_readlane(__float_as_int(vR0), k));
        const float r1 = __int_as_float(__builtin_amdgcn_readlane(__float_as_int(vR1), k));
        const float d0 = __int_as_float(__builtin_amdgcn_readlane(__float_as_int(vD0), k));
        const float d1 = __int_as_float(__builtin_amdgcn_readlane(__float_as_int(vD1), k));
        const float l0 = __int_as_float(__builtin_amdgcn_readlane(__float_as_int(vL0), k));
        const float l1 = __int_as_float(__builtin_amdgcn_readlane(__float_as_int(vL1), k));
        const float dr0 = r0 - Rj;
        const float dr1 = r1 - Rj;
        const float e0 = __builtin_amdgcn_exp2f(-(dr0 * dr0));  // exp(-drt^2/2)
        const float e1 = __builtin_amdgcn_exp2f(-(dr1 * dr1));
        const float t0 = __builtin_amdgcn_rcpf(fmaf(0.3916993f, fabsf(dr0), 1.0f));
        const float t1 = __builtin_amdgcn_rcpf(fmaf(0.3916993f, fabsf(dr1), 1.0f));
        const float u0 = t0 * fmaf(t0, fmaf(t0, 0.3739278f, -0.0479399f), 0.1740121f) * e0;
        const float u1 = t1 * fmaf(t1, fmaf(t1, 0.3739278f, -0.0479399f), 0.1740121f) * e1;
        a0 = fmaf(d0, e0, a0);
        a1 = fmaf(d1, e1, a1);
        b0 = fmaf(copysignf(l0, dr0), 0.5f - u0, b0);
        b1 = fmaf(copysignf(l1, dr1), 0.5f - u1, b1);
    }
    P[(size_t)blockIdx.y * n + j] = make_float2(a0 + a1, b0 + b1);
}

// out = (1/n) * sum_j d_j * (R_j - g2_j - log(c1*A_j + eps) + log(invn*B_j + eps))
__global__ __launch_bounds__(TPB) void finalize_kernel(
    const float2* __restrict__ P, const float* __restrict__ m_z,
    const float* __restrict__ y, const float* __restrict__ delta,
    float* __restrict__ out, float c1, float invn, int n) {
    const int j = blockIdx.x * TPB + threadIdx.x;
    float sa = 0.0f, sb = 0.0f;
    for (int b = 0; b < IB; ++b) {               // coalesced float2 reads
        const float2 v = P[(size_t)b * n + j];
        sa += v.x;
        sb += v.y;
    }
    const float d = delta[j];
    const float R = m_z[2 * j] + __logf(y[j]);
    float term = d * (R - m_z[2 * j + 1] - __logf(fmaf(c1, sa, EPSF))
                                         + __logf(fmaf(invn, sb, EPSF)));
    for (int o = 32; o > 0; o >>= 1) term += __shfl_down(term, o, 64);
    __shared__ float wsum[TPB / 64];
    if ((threadIdx.x & 63) == 0) wsum[threadIdx.x >> 6] = term;
    __syncthreads();
    if (threadIdx.x == 0) {
        float ssum = 0.0f;
        for (int w = 0; w < TPB / 64; ++w) ssum += wsum[w];
        atomicAdd(out, ssum * invn);
    }
}

extern "C" void kernel_launch(void* const* d_in, const int* in_sizes, int n_in,
                              void* d_out, int out_size, void* d_ws, size_t ws_size,
                              hipStream_t stream) {
    const float* m_z   = (const float*)d_in[0];   // (n,2)
    const float* y     = (const float*)d_in[1];   // (n,1)
    const float* delta = (const float*)d_in[2];   // (n,1)
    float* out = (float*)d_out;
    const int n = in_sizes[1];                    // 8192

    float2* P = (float2*)d_ws;                    // IB * n * 8 B = 4 MB

    const double h = 1.3 * pow((double)n, -0.2);
    const double k = 1.1774100225154747;          // sqrt(2 ln 2)
    const float inv_hk = (float)(1.0 / (h * k));
    const float c1 = (float)(0.3989422804014327 / ((double)n * h)); // INV_SQRT_2PI/(n*h)
    const float invn = 1.0f / (float)n;
    const int span = n / IB;                      // 128

    const int nblk = (n + TPB - 1) / TPB;         // 32
    dim3 grid(nblk, IB);                          // 2048 blocks = 8/CU
    pair_kernel<<<grid, TPB, 0, stream>>>(m_z, y, delta, P, out, inv_hk, n, span);
    finalize_kernel<<<nblk, TPB, 0, stream>>>(P, m_z, y, delta, out, c1, invn, n);
}